// Round 6
// baseline (7636.483 us; speedup 1.0000x reference)
//
#include <hip/hip_runtime.h>
#include <cstdint>

// ---------------- problem constants ----------------
constexpr int B_ = 4, N_ = 16384, M_ = 2048;
constexpr int COLS0 = B_ * M_ * 32;   // 262144
constexpr int COLS1 = B_ * M_ * 64;   // 524288

// ---------------- FPS partitioning ----------------
constexpr int FPS_G   = 8;                       // blocks per batch
constexpr int FPS_T   = 512;                     // threads per fps block
constexpr int FPS_PPT = N_ / FPS_G / FPS_T;      // 4 points per thread (pure registers)

// ---------------- workspace layout (bytes) ----------------
constexpr size_t OFF_NEWXYZ = 0;                                   // B*3*M fp32
constexpr size_t OFF_NIDX0  = (size_t)B_ * 3 * M_ * 4;             // 98304
constexpr size_t OFF_NIDX1  = OFF_NIDX0 + (size_t)COLS0 * 4;
constexpr size_t OFF_STATS  = OFF_NIDX1 + (size_t)COLS1 * 4;
constexpr size_t STATS_VALS = 64 * 2 * 128;                        // doubles per layer region
constexpr size_t OFF_COEF   = OFF_STATS + 6 * STATS_VALS * 8;      // 6 x 128 float4
constexpr size_t OFF_SLOT   = OFF_COEF + 6 * 128 * 16;             // fps sync slots
constexpr size_t SLOT_BYTES = (size_t)B_ * 2 * FPS_G * 64;         // ping-pong, 64B line each
constexpr size_t OFF_Z      = OFF_SLOT + SLOT_BYTES;
// Z: per-64-column records [rec][96 ch][64 lanes] fp32; COLS1/64 recs -> 201.3 MB
constexpr int ZSTRIDE = 96 * 64;                                   // floats per record

// ---------------- FPS v6 (unchanged from R5: passed, 3.85ms, near cross-XCD sync floor) ------
__global__ __launch_bounds__(FPS_T) void fps_kernel(const float* __restrict__ xyz,
                                                    float* __restrict__ newxyz,
                                                    float* __restrict__ outxyz,
                                                    unsigned long long* __restrict__ slots) {
#pragma clang fp contract(off)
  int bid = blockIdx.x;
  int b = bid >> 3, g = bid & 7;                  // batch, group-within-batch
  int t = threadIdx.x, lane = t & 63, wid = t >> 6;
  const float* xb = xyz + (size_t)b * 3 * N_;
  int nbase = g * (N_ / FPS_G) + t;               // this thread's points: nbase + j*FPS_T
  float px[FPS_PPT], py[FPS_PPT], pz[FPS_PPT], dd[FPS_PPT];
#pragma unroll
  for (int j = 0; j < FPS_PPT; ++j) {
    int n = nbase + j * FPS_T;
    px[j] = xb[n]; py[j] = xb[N_ + n]; pz[j] = xb[2 * N_ + n];
    dd[j] = 1e10f;
    asm volatile("" : "+v"(px[j]), "+v"(py[j]), "+v"(pz[j]));
  }
  __shared__ unsigned long long s_red[2][FPS_T / 64];
  __shared__ unsigned long long s_win[2];
  size_t base = (size_t)b * 3 * M_;
  float fx = xb[0], fy = xb[N_], fz = xb[2 * N_];
  if (g == 0 && t == 0) {
    newxyz[base] = fx; newxyz[base + M_] = fy; newxyz[base + 2 * M_] = fz;
    outxyz[base] = fx; outxyz[base + M_] = fy; outxyz[base + 2 * M_] = fz;
  }
  unsigned long long* sb = slots + (size_t)b * 2 * FPS_G * 8;   // 8 u64 per 64B line
  for (int s = 1; s < M_; ++s) {
    float bv = -1.f; int bi = 0;
#pragma unroll
    for (int j = 0; j < FPS_PPT; ++j) {
      float dx = px[j] - fx, dy = py[j] - fy, dz = pz[j] - fz;
      float d = (dx * dx + dy * dy) + dz * dz;    // verbatim ref arithmetic (no FMA)
      float dm = dd[j];
      if (d < dm) dm = d;
      dd[j] = dm;
      if (dm > bv) { bv = dm; bi = nbase + j * FPS_T; }  // in-thread tie -> smaller n kept
    }
    unsigned long long key =
        ((unsigned long long)__float_as_uint(bv) << 32) |
        (unsigned)(((unsigned)s << 14) | (unsigned)(0x3FFF - bi));
#pragma unroll
    for (int off = 1; off < 64; off <<= 1) {
      unsigned long long o = __shfl_xor(key, off);
      if (o > key) key = o;
    }
    int p = s & 1;
    if (lane == 0) s_red[p][wid] = key;
    __syncthreads();
    if (wid == 0) {
      unsigned long long bk = s_red[p][lane & 7];
#pragma unroll
      for (int off = 1; off < 8; off <<= 1) {
        unsigned long long o = __shfl_xor(bk, off);
        if (o > bk) bk = o;
      }
      unsigned long long kk = 0;
      if (lane < FPS_G) {
        unsigned long long* sp = sb + ((size_t)p * FPS_G + lane) * 8;
        if (lane == g) atomicExch(sp, bk);        // publish own block's key
        unsigned long long v;
        unsigned tag = (unsigned)s;
        for (int it = 0; it < (1 << 18); ++it) {
          v = atomicAdd(sp, 0ull);                // coherent RMW read
          if ((unsigned)((v >> 14) & 0x3FFFFull) == tag) break;
          __builtin_amdgcn_s_sleep(1);
        }
        kk = v;
      }
#pragma unroll
      for (int off = 1; off < 8; off <<= 1) {
        unsigned long long o = __shfl_xor(kk, off);
        if (o > kk) kk = o;
      }
      if (lane == 0) s_win[p] = kk;
    }
    __syncthreads();
    unsigned long long k = s_win[p];
    int w = 0x3FFF - (int)(k & 0x3FFFull);
    fx = xb[w]; fy = xb[N_ + w]; fz = xb[2 * N_ + w];
    if (g == 0 && t == 0) {
      newxyz[base + s] = fx; newxyz[base + M_ + s] = fy; newxyz[base + 2 * M_ + s] = fz;
      outxyz[base + s] = fx; outxyz[base + M_ + s] = fy; outxyz[base + 2 * M_ + s] = fz;
    }
  }
}

// ---------------- ball query: wave per center, ballot-prefix, FMA dot (unchanged) -------------
template <int KNB>
__global__ __launch_bounds__(256) void bq_kernel(const float* __restrict__ xyz,
                                                 const float* __restrict__ newxyz,
                                                 int* __restrict__ nidx, float r2) {
#pragma clang fp contract(off)
  int t = threadIdx.x, lane = t & 63, wq = t >> 6;
  int q = blockIdx.x * 4 + wq;               // q < B*M
  int b = q >> 11, m = q & 2047;
  const float* xb = xyz + (size_t)b * 3 * N_;
  float cx = newxyz[((size_t)b * 3 + 0) * M_ + m];
  float cy = newxyz[((size_t)b * 3 + 1) * M_ + m];
  float cz = newxyz[((size_t)b * 3 + 2) * M_ + m];
  float sqc = (cx * cx + cy * cy) + cz * cz;         // no fma
  int found = 0, first = 0;
  for (int c = 0; c < N_ / 64; ++c) {
    int n = c * 64 + lane;
    float x = xb[n], y = xb[N_ + n], z = xb[2 * N_ + n];
    float sqx = (x * x + y * y) + z * z;             // no fma
    float dot = fmaf(cz, z, fmaf(cy, y, cx * x));    // fma chain (proven ref rounding)
    float d2 = (sqc + sqx) - 2.0f * dot;
    bool in = d2 < r2;
    unsigned long long mask = __ballot(in);
    if (mask) {
      if (found == 0) first = c * 64 + (__ffsll((long long)mask) - 1);
      int pos = found + __popcll(mask & ((1ull << lane) - 1ull));
      if (in && pos < KNB) nidx[(size_t)q * KNB + pos] = n;
      found += __popcll(mask);
      if (found >= KNB) break;
    }
  }
  if (found < KNB) {
    int fill = (found == 0) ? 0 : first;
    for (int s = found + lane; s < KNB; s += 64) nidx[(size_t)q * KNB + s] = fill;
  }
}

// ---------------- per-channel stats: fp32 butterfly partials -> f64 bucketed atomics ----------
__device__ __forceinline__ void stat_accum(float acc, int o, int cout, double* stats,
                                           int part, int lane) {
  float v1 = acc, v2 = acc * acc;
#pragma unroll
  for (int off = 1; off < 64; off <<= 1) {
    v1 += __shfl_xor(v1, off);
    v2 += __shfl_xor(v2, off);
  }
  if (lane == 0) {
    atomicAdd(stats + ((size_t)part * 2 + 0) * cout + o, (double)v1);
    atomicAdd(stats + ((size_t)part * 2 + 1) * cout + o, (double)v2);
  }
}

// ---------------- conv R6: block = 1 record; x-tile staged in LDS once; waves split outputs --
// R5 post-mortem: VGPR=44/60 with x[67]/x[64] arrays => x NOT register-resident; re-read from
// L1/L2 per output iteration (convL0: scattered feat re-gathers). LDS tile makes residency
// structural. 8 accumulators per wave => 1 ds_read feeds 8 FMAs (11% LDS overhead). Per-column
// c-order accumulation, BN formula, butterflies, pool shuffles verbatim.
template <int CIN, int G>
__device__ __forceinline__ void conv_sweep(const float* __restrict__ w, int o0,
                                           const float* sx, int lane, float* acc) {
#pragma unroll
  for (int k = 0; k < G; ++k) acc[k] = 0.f;
#pragma unroll 16
  for (int c = 0; c < CIN; ++c) {
    float xv = sx[c * 64 + lane];
#pragma unroll
    for (int k = 0; k < G; ++k) acc[k] += w[(size_t)(o0 + 4 * k) * CIN + c] * xv;
  }
}

// stage BN(ReLU(zr)) tile -> sx, float4 path (Z records are 16B-aligned)
template <int CIN>
__device__ __forceinline__ void stage_bn(const float* __restrict__ zr,
                                         const float4* __restrict__ coefIn,
                                         float* sx, int t) {
  const float4* zr4 = (const float4*)zr;
  float4* sx4 = (float4*)sx;
  for (int e = t; e < CIN * 16; e += 256) {
    int c = e >> 4;
    float4 v = zr4[e];
    float4 cf = coefIn[c];
    float4 r;
    r.x = fmaxf(((v.x - cf.x) * cf.y) * cf.z + cf.w, 0.f);
    r.y = fmaxf(((v.y - cf.x) * cf.y) * cf.z + cf.w, 0.f);
    r.z = fmaxf(((v.z - cf.x) * cf.y) * cf.z + cf.w, 0.f);
    r.w = fmaxf(((v.w - cf.x) * cf.y) * cf.z + cf.w, 0.f);
    sx4[e] = r;
  }
}

// ---------------- layer 0: gather once -> LDS -> conv(67->64) + stats ------------------------
template <int KNB>
__global__ __launch_bounds__(256) void convL0_kernel(
    const float* __restrict__ w0, const float* __restrict__ xyz,
    const float* __restrict__ feat, const int* __restrict__ nidx,
    const float* __restrict__ newxyz, float* __restrict__ Z, double* __restrict__ stats) {
  __shared__ float sx[67 * 64];                 // 17152 B
  __shared__ int snb[64];
  int rec = blockIdx.x, t = threadIdx.x, lane = t & 63, wid = t >> 6;
  if (t < 64) snb[t] = nidx[(size_t)rec * 64 + t];
  __syncthreads();
  for (int e = t; e < 67 * 64; e += 256) {      // each input element fetched exactly once
    int c = e >> 6, l = e & 63;
    int col = rec * 64 + l;
    int b = col / (M_ * KNB);
    int rem = col - b * (M_ * KNB);
    int m = rem / KNB;
    int n = snb[l];
    float v;
    if (c < 3) v = xyz[((size_t)b * 3 + c) * N_ + n] - newxyz[((size_t)b * 3 + c) * M_ + m];
    else       v = feat[((size_t)b * 64 + (c - 3)) * N_ + n];
    sx[e] = v;
  }
  __syncthreads();
  float* zr = Z + (size_t)rec * ZSTRIDE;
  int part = rec & 63;
  float acc[8];
#pragma unroll
  for (int g = 0; g < 2; ++g) {                 // 16 outs/wave: o = wid + 32g + 4k
    int o0 = wid + 32 * g;
    conv_sweep<67, 8>(w0, o0, sx, lane, acc);
#pragma unroll
    for (int k = 0; k < 8; ++k) {
      int o = o0 + 4 * k;
      zr[o * 64 + lane] = acc[k];
      stat_accum(acc[k], o, 64, stats, part, lane);
    }
  }
}

// ---------------- mid layer: BN-stage -> conv -> in-place store + stats ----------------------
template <int CIN, int COUT>
__global__ __launch_bounds__(256) void convMid_kernel(
    const float* __restrict__ w, const float4* __restrict__ coefIn,
    float* __restrict__ Z, double* __restrict__ stats) {
  __shared__ float sx[CIN * 64];
  int rec = blockIdx.x, t = threadIdx.x, lane = t & 63, wid = t >> 6;
  float* zr = Z + (size_t)rec * ZSTRIDE;
  stage_bn<CIN>(zr, coefIn, sx, t);
  __syncthreads();                              // all reads done -> safe in-place overwrite
  int part = rec & 63;
  float acc[8];
#pragma unroll
  for (int g = 0; g < COUT / 32; ++g) {
    int o0 = wid + 32 * g;
    conv_sweep<CIN, 8>(w, o0, sx, lane, acc);
#pragma unroll
    for (int k = 0; k < 8; ++k) {
      int o = o0 + 4 * k;
      zr[o * 64 + lane] = acc[k];
      stat_accum(acc[k], o, COUT, stats, part, lane);
    }
  }
}

// ---------------- last layer, pass A: stats only ---------------------------------------------
template <int CIN>
__global__ __launch_bounds__(256) void convLastStats_kernel(
    const float* __restrict__ w, const float4* __restrict__ coefIn,
    const float* __restrict__ Z, double* __restrict__ stats) {
  __shared__ float sx[CIN * 64];
  int rec = blockIdx.x, t = threadIdx.x, lane = t & 63, wid = t >> 6;
  const float* zr = Z + (size_t)rec * ZSTRIDE;
  stage_bn<CIN>(zr, coefIn, sx, t);
  __syncthreads();
  int part = rec & 63;
  float acc[8];
#pragma unroll
  for (int g = 0; g < 4; ++g) {                 // 128 outs
    int o0 = wid + 32 * g;
    conv_sweep<CIN, 8>(w, o0, sx, lane, acc);
#pragma unroll
    for (int k = 0; k < 8; ++k) stat_accum(acc[k], o0 + 4 * k, 128, stats, part, lane);
  }
}

// ---------------- last layer, pass B: recompute conv + BN + ReLU + max over K + write --------
template <int CIN, int KNB>
__global__ __launch_bounds__(256) void convLastPool_kernel(
    const float* __restrict__ w, const float4* __restrict__ coefIn,
    const float4* __restrict__ coefOut,
    const float* __restrict__ Z, float* __restrict__ outFeats, int chBase) {
  __shared__ float sx[CIN * 64];
  int rec = blockIdx.x, t = threadIdx.x, lane = t & 63, wid = t >> 6;
  const float* zr = Z + (size_t)rec * ZSTRIDE;
  stage_bn<CIN>(zr, coefIn, sx, t);
  __syncthreads();
  float acc[8];
#pragma unroll
  for (int g = 0; g < 4; ++g) {
    int o0 = wid + 32 * g;
    conv_sweep<CIN, 8>(w, o0, sx, lane, acc);
#pragma unroll
    for (int k = 0; k < 8; ++k) {
      int o = o0 + 4 * k;
      float4 cf = coefOut[o];
      float z = fmaxf(((acc[k] - cf.x) * cf.y) * cf.z + cf.w, 0.f);
      if (KNB == 64) {
#pragma unroll
        for (int off = 1; off < 64; off <<= 1) z = fmaxf(z, __shfl_xor(z, off));
        if (lane == 0) {
          int b = rec >> 11, m = rec & 2047;
          outFeats[((size_t)b * 256 + chBase + o) * M_ + m] = z;
        }
      } else {                                  // KNB == 32: two groups per wave
#pragma unroll
        for (int off = 1; off < 32; off <<= 1) z = fmaxf(z, __shfl_xor(z, off));
        if ((lane & 31) == 0) {
          int grp = rec * 2 + (lane >> 5);
          int b = grp >> 11, m = grp & 2047;
          outFeats[((size_t)b * 256 + chBase + o) * M_ + m] = z;
        }
      }
    }
  }
}

// ---------------- fold fp64 BN stats into per-channel (mu, rstd, g, b) ----------------
__global__ void coef_kernel(const double* __restrict__ stats, const float* __restrict__ g,
                            const float* __restrict__ bb, float4* __restrict__ coef,
                            int cout, double invcnt) {
  int ch = threadIdx.x;
  if (ch >= cout) return;
  double s1 = 0.0, s2 = 0.0;
  for (int p = 0; p < 64; ++p) {
    s1 += stats[((size_t)p * 2 + 0) * cout + ch];
    s2 += stats[((size_t)p * 2 + 1) * cout + ch];
  }
  double mean = s1 * invcnt;
  double var = s2 * invcnt - mean * mean;
  double rstd = 1.0 / sqrt(var + 1e-5);
  coef[ch] = make_float4((float)mean, (float)rstd, g[ch], bb[ch]);
}

// ---------------- launcher ----------------
extern "C" void kernel_launch(void* const* d_in, const int* in_sizes, int n_in,
                              void* d_out, int out_size, void* d_ws, size_t ws_size,
                              hipStream_t stream) {
  const float* xyz  = (const float*)d_in[0];
  const float* feat = (const float*)d_in[1];
  const float* w00 = (const float*)d_in[2],  *g00 = (const float*)d_in[3],  *b00 = (const float*)d_in[4];
  const float* w01 = (const float*)d_in[5],  *g01 = (const float*)d_in[6],  *b01 = (const float*)d_in[7];
  const float* w02 = (const float*)d_in[8],  *g02 = (const float*)d_in[9],  *b02 = (const float*)d_in[10];
  const float* w10 = (const float*)d_in[11], *g10 = (const float*)d_in[12], *b10 = (const float*)d_in[13];
  const float* w11 = (const float*)d_in[14], *g11 = (const float*)d_in[15], *b11 = (const float*)d_in[16];
  const float* w12 = (const float*)d_in[17], *g12 = (const float*)d_in[18], *b12 = (const float*)d_in[19];

  char* ws = (char*)d_ws;
  float*  newxyz = (float*)(ws + OFF_NEWXYZ);
  int*    nidx0  = (int*)(ws + OFF_NIDX0);
  int*    nidx1  = (int*)(ws + OFF_NIDX1);
  double* stats  = (double*)(ws + OFF_STATS);
  float4* coef   = (float4*)(ws + OFF_COEF);
  unsigned long long* slots = (unsigned long long*)(ws + OFF_SLOT);
  float*  Z      = (float*)(ws + OFF_Z);
  float* outF = (float*)d_out;
  float* outFeats = outF + (size_t)B_ * 3 * M_;

  hipMemsetAsync(ws + OFF_STATS, 0, 6 * STATS_VALS * 8, stream);
  hipMemsetAsync(ws + OFF_SLOT, 0, SLOT_BYTES, stream);   // tags invalid for all steps
  fps_kernel<<<B_ * FPS_G, FPS_T, 0, stream>>>(xyz, newxyz, outF, slots);
  bq_kernel<32><<<(B_ * M_) / 4, 256, 0, stream>>>(xyz, newxyz, nidx0, (float)(0.2 * 0.2));
  bq_kernel<64><<<(B_ * M_) / 4, 256, 0, stream>>>(xyz, newxyz, nidx1, (float)(0.4 * 0.4));

  float4* c00 = coef + 0 * 128; float4* c01 = coef + 1 * 128; float4* c02 = coef + 2 * 128;
  float4* c10 = coef + 3 * 128; float4* c11 = coef + 4 * 128; float4* c12 = coef + 5 * 128;
  double* st0 = stats + 0 * STATS_VALS; double* st1 = stats + 1 * STATS_VALS;
  double* st2 = stats + 2 * STATS_VALS; double* st3 = stats + 3 * STATS_VALS;
  double* st4 = stats + 4 * STATS_VALS; double* st5 = stats + 5 * STATS_VALS;
  int gb0 = COLS0 / 64, gb1 = COLS1 / 64;       // ONE record per 256-thr block now

  // ---- scale 0 (K=32): 67->64->64->128 ----
  convL0_kernel<32><<<gb0, 256, 0, stream>>>(w00, xyz, feat, nidx0, newxyz, Z, st0);
  coef_kernel<<<1, 128, 0, stream>>>(st0, g00, b00, c00, 64, 1.0 / COLS0);
  convMid_kernel<64, 64><<<gb0, 256, 0, stream>>>(w01, c00, Z, st1);
  coef_kernel<<<1, 128, 0, stream>>>(st1, g01, b01, c01, 64, 1.0 / COLS0);
  convLastStats_kernel<64><<<gb0, 256, 0, stream>>>(w02, c01, Z, st2);
  coef_kernel<<<1, 128, 0, stream>>>(st2, g02, b02, c02, 128, 1.0 / COLS0);
  convLastPool_kernel<64, 32><<<gb0, 256, 0, stream>>>(w02, c01, c02, Z, outFeats, 0);

  // ---- scale 1 (K=64): 67->64->96->128 ----
  convL0_kernel<64><<<gb1, 256, 0, stream>>>(w10, xyz, feat, nidx1, newxyz, Z, st3);
  coef_kernel<<<1, 128, 0, stream>>>(st3, g10, b10, c10, 64, 1.0 / COLS1);
  convMid_kernel<64, 96><<<gb1, 256, 0, stream>>>(w11, c10, Z, st4);
  coef_kernel<<<1, 128, 0, stream>>>(st4, g11, b11, c11, 96, 1.0 / COLS1);
  convLastStats_kernel<96><<<gb1, 256, 0, stream>>>(w12, c11, Z, st5);
  coef_kernel<<<1, 128, 0, stream>>>(st5, g12, b12, c12, 128, 1.0 / COLS1);
  convLastPool_kernel<96, 64><<<gb1, 256, 0, stream>>>(w12, c11, c12, Z, outFeats, 128);
}

// Round 7
// 5058.953 us; speedup vs baseline: 1.5095x; 1.5095x over previous
//
#include <hip/hip_runtime.h>
#include <cstdint>

// ---------------- problem constants ----------------
constexpr int B_ = 4, N_ = 16384, M_ = 2048;
constexpr int COLS0 = B_ * M_ * 32;   // 262144
constexpr int COLS1 = B_ * M_ * 64;   // 524288

// ---------------- workspace layout (bytes) ----------------
constexpr size_t OFF_NEWXYZ = 0;                                   // B*3*M fp32
constexpr size_t OFF_NIDX0  = (size_t)B_ * 3 * M_ * 4;             // 98304
constexpr size_t OFF_NIDX1  = OFF_NIDX0 + (size_t)COLS0 * 4;
constexpr size_t OFF_STATS  = OFF_NIDX1 + (size_t)COLS1 * 4;
constexpr size_t STATS_VALS = 64 * 2 * 128;                        // doubles per layer region
constexpr size_t OFF_COEF   = OFF_STATS + 6 * STATS_VALS * 8;      // 6 x 128 float4
constexpr size_t OFF_Z      = OFF_COEF + 6 * 128 * 16;
// Z: per-64-column records [rec][96 ch][64 lanes] fp32; COLS1/64 recs -> 201.3 MB
constexpr int ZSTRIDE = 96 * 64;                                   // floats per record

// ---------------- FPS: R0's proven single-block kernel (3673 us measured) --------------------
// Multi-block variants (R4-R6) bottomed at 3.85-3.95ms: cross-XCD coherent-atomic sync floor
// ~1.2-1.5us/step. This version's step cost (~1.8us) is L1/L2 reload of the spilled point set,
// fully hidden pipelining-wise; it remains the best measured fps on this hardware.
__global__ __launch_bounds__(512) void fps_kernel(const float* __restrict__ xyz,
                                                  float* __restrict__ newxyz,
                                                  float* __restrict__ outxyz) {
#pragma clang fp contract(off)
  int b = blockIdx.x, t = threadIdx.x;
  const float* xb = xyz + (size_t)b * 3 * N_;
  float px[32], py[32], pz[32], dd[32];
#pragma unroll
  for (int i = 0; i < 32; ++i) {
    int n = t + (i << 9);
    px[i] = xb[n]; py[i] = xb[N_ + n]; pz[i] = xb[2 * N_ + n];
    dd[i] = 1e10f;
  }
  __shared__ float s_out[3 * M_];
  __shared__ unsigned long long s_red[8];
  __shared__ int s_w;
  float fx = xb[0], fy = xb[N_], fz = xb[2 * N_];
  if (t == 0) { s_out[0] = fx; s_out[M_] = fy; s_out[2 * M_] = fz; }
  int lane = t & 63, wid = t >> 6;
  for (int s = 1; s < M_; ++s) {
    float bv = -1.f; int bi = 0;
#pragma unroll
    for (int i = 0; i < 32; ++i) {
      float dx = px[i] - fx, dy = py[i] - fy, dz = pz[i] - fz;
      float d = (dx * dx + dy * dy) + dz * dz;   // verbatim ref arithmetic (no FMA)
      float dm = dd[i];
      if (d < dm) dm = d;
      dd[i] = dm;
      if (dm > bv) { bv = dm; bi = t + (i << 9); }  // in-thread tie -> smaller n kept
    }
    // key: dist bits (>=0, monotone) high, ~idx low => max key = max dist, tie -> min idx
    unsigned long long key =
        ((unsigned long long)__float_as_uint(bv) << 32) | (unsigned)(0xFFFFFFFFu - (unsigned)bi);
#pragma unroll
    for (int off = 1; off < 64; off <<= 1) {
      unsigned long long o = __shfl_xor(key, off);
      if (o > key) key = o;
    }
    if (lane == 0) s_red[wid] = key;
    __syncthreads();
    if (wid == 0) {
      unsigned long long k2 = (lane < 8) ? s_red[lane] : 0ull;
#pragma unroll
      for (int off = 1; off < 8; off <<= 1) {
        unsigned long long o = __shfl_xor(k2, off);
        if (o > k2) k2 = o;
      }
      if (lane == 0) s_w = (int)(0xFFFFFFFFu - (unsigned)(k2 & 0xFFFFFFFFull));
    }
    __syncthreads();
    int w = s_w;
    fx = xb[w]; fy = xb[N_ + w]; fz = xb[2 * N_ + w];
    if (t == 0) { s_out[s] = fx; s_out[M_ + s] = fy; s_out[2 * M_ + s] = fz; }
  }
  __syncthreads();
  for (int e = t; e < 3 * M_; e += 512) {
    float v = s_out[e];
    newxyz[(size_t)b * 3 * M_ + e] = v;
    outxyz[(size_t)b * 3 * M_ + e] = v;
  }
}

// ---------------- ball query: wave per center, ballot-prefix, FMA dot (unchanged) -------------
template <int KNB>
__global__ __launch_bounds__(256) void bq_kernel(const float* __restrict__ xyz,
                                                 const float* __restrict__ newxyz,
                                                 int* __restrict__ nidx, float r2) {
#pragma clang fp contract(off)
  int t = threadIdx.x, lane = t & 63, wq = t >> 6;
  int q = blockIdx.x * 4 + wq;               // q < B*M
  int b = q >> 11, m = q & 2047;
  const float* xb = xyz + (size_t)b * 3 * N_;
  float cx = newxyz[((size_t)b * 3 + 0) * M_ + m];
  float cy = newxyz[((size_t)b * 3 + 1) * M_ + m];
  float cz = newxyz[((size_t)b * 3 + 2) * M_ + m];
  float sqc = (cx * cx + cy * cy) + cz * cz;         // no fma
  int found = 0, first = 0;
  for (int c = 0; c < N_ / 64; ++c) {
    int n = c * 64 + lane;
    float x = xb[n], y = xb[N_ + n], z = xb[2 * N_ + n];
    float sqx = (x * x + y * y) + z * z;             // no fma
    float dot = fmaf(cz, z, fmaf(cy, y, cx * x));    // fma chain (proven ref rounding)
    float d2 = (sqc + sqx) - 2.0f * dot;
    bool in = d2 < r2;
    unsigned long long mask = __ballot(in);
    if (mask) {
      if (found == 0) first = c * 64 + (__ffsll((long long)mask) - 1);
      int pos = found + __popcll(mask & ((1ull << lane) - 1ull));
      if (in && pos < KNB) nidx[(size_t)q * KNB + pos] = n;
      found += __popcll(mask);
      if (found >= KNB) break;
    }
  }
  if (found < KNB) {
    int fill = (found == 0) ? 0 : first;
    for (int s = found + lane; s < KNB; s += 64) nidx[(size_t)q * KNB + s] = fill;
  }
}

// ---------------- per-channel stats: fp32 butterfly partials -> f64 bucketed atomics ----------
__device__ __forceinline__ void stat_accum(float acc, int o, int cout, double* stats,
                                           int part, int lane) {
  float v1 = acc, v2 = acc * acc;
#pragma unroll
  for (int off = 1; off < 64; off <<= 1) {
    v1 += __shfl_xor(v1, off);
    v2 += __shfl_xor(v2, off);
  }
  if (lane == 0) {
    atomicAdd(stats + ((size_t)part * 2 + 0) * cout + o, (double)v1);
    atomicAdd(stats + ((size_t)part * 2 + 1) * cout + o, (double)v2);
  }
}

// ---------------- conv R7: R6's LDS tile + UNIFORM (sgpr) weight base ------------------------
// R6 post-mortem: o0 = wid+32g is wave-uniform by construction but LLVM can't prove it, so
// weight loads compiled as per-lane global_load_dword (divergent) instead of s_load -> 2.3x
// regression. readfirstlane(o0) is exact here and forces the weight base into an SGPR: the
// whole inner loop becomes 1 conflict-free ds_read_b32 + 8 s-operand FMAs per c.
template <int CIN, int G>
__device__ __forceinline__ void conv_sweep(const float* __restrict__ w, int o0,
                                           const float* sx, int lane, float* acc) {
  int o0u = __builtin_amdgcn_readfirstlane(o0);       // exact: o0 is wave-uniform
  const float* wb = w + (size_t)o0u * CIN;            // SGPR base -> s_load weights
#pragma unroll
  for (int k = 0; k < G; ++k) acc[k] = 0.f;
#pragma unroll 8
  for (int c = 0; c < CIN; ++c) {
    float xv = sx[c * 64 + lane];
#pragma unroll
    for (int k = 0; k < G; ++k) acc[k] += wb[(size_t)(4 * k) * CIN + c] * xv;
  }
}

// stage BN(ReLU(zr)) tile -> sx, float4 path (Z records are 16B-aligned)
template <int CIN>
__device__ __forceinline__ void stage_bn(const float* __restrict__ zr,
                                         const float4* __restrict__ coefIn,
                                         float* sx, int t) {
  const float4* zr4 = (const float4*)zr;
  float4* sx4 = (float4*)sx;
  for (int e = t; e < CIN * 16; e += 256) {
    int c = e >> 4;
    float4 v = zr4[e];
    float4 cf = coefIn[c];
    float4 r;
    r.x = fmaxf(((v.x - cf.x) * cf.y) * cf.z + cf.w, 0.f);
    r.y = fmaxf(((v.y - cf.x) * cf.y) * cf.z + cf.w, 0.f);
    r.z = fmaxf(((v.z - cf.x) * cf.y) * cf.z + cf.w, 0.f);
    r.w = fmaxf(((v.w - cf.x) * cf.y) * cf.z + cf.w, 0.f);
    sx4[e] = r;
  }
}

// ---------------- layer 0: gather once -> LDS -> conv(67->64) + stats ------------------------
template <int KNB>
__global__ __launch_bounds__(256) void convL0_kernel(
    const float* __restrict__ w0, const float* __restrict__ xyz,
    const float* __restrict__ feat, const int* __restrict__ nidx,
    const float* __restrict__ newxyz, float* __restrict__ Z, double* __restrict__ stats) {
  __shared__ float sx[67 * 64];                 // 17152 B
  __shared__ int snb[64];
  int rec = blockIdx.x, t = threadIdx.x, lane = t & 63, wid = t >> 6;
  if (t < 64) snb[t] = nidx[(size_t)rec * 64 + t];
  __syncthreads();
  for (int e = t; e < 67 * 64; e += 256) {      // each input element fetched exactly once
    int c = e >> 6, l = e & 63;
    int col = rec * 64 + l;
    int b = col / (M_ * KNB);
    int rem = col - b * (M_ * KNB);
    int m = rem / KNB;
    int n = snb[l];
    float v;
    if (c < 3) v = xyz[((size_t)b * 3 + c) * N_ + n] - newxyz[((size_t)b * 3 + c) * M_ + m];
    else       v = feat[((size_t)b * 64 + (c - 3)) * N_ + n];
    sx[e] = v;
  }
  __syncthreads();
  float* zr = Z + (size_t)rec * ZSTRIDE;
  int part = rec & 63;
  float acc[8];
#pragma unroll
  for (int g = 0; g < 2; ++g) {                 // 16 outs/wave: o = wid + 32g + 4k
    int o0 = wid + 32 * g;
    conv_sweep<67, 8>(w0, o0, sx, lane, acc);
#pragma unroll
    for (int k = 0; k < 8; ++k) {
      int o = o0 + 4 * k;
      zr[o * 64 + lane] = acc[k];
      stat_accum(acc[k], o, 64, stats, part, lane);
    }
  }
}

// ---------------- mid layer: BN-stage -> conv -> in-place store + stats ----------------------
template <int CIN, int COUT>
__global__ __launch_bounds__(256) void convMid_kernel(
    const float* __restrict__ w, const float4* __restrict__ coefIn,
    float* __restrict__ Z, double* __restrict__ stats) {
  __shared__ float sx[CIN * 64];
  int rec = blockIdx.x, t = threadIdx.x, lane = t & 63, wid = t >> 6;
  float* zr = Z + (size_t)rec * ZSTRIDE;
  stage_bn<CIN>(zr, coefIn, sx, t);
  __syncthreads();                              // all reads done -> safe in-place overwrite
  int part = rec & 63;
  float acc[8];
#pragma unroll
  for (int g = 0; g < COUT / 32; ++g) {
    int o0 = wid + 32 * g;
    conv_sweep<CIN, 8>(w, o0, sx, lane, acc);
#pragma unroll
    for (int k = 0; k < 8; ++k) {
      int o = o0 + 4 * k;
      zr[o * 64 + lane] = acc[k];
      stat_accum(acc[k], o, COUT, stats, part, lane);
    }
  }
}

// ---------------- last layer, pass A: stats only ---------------------------------------------
template <int CIN>
__global__ __launch_bounds__(256) void convLastStats_kernel(
    const float* __restrict__ w, const float4* __restrict__ coefIn,
    const float* __restrict__ Z, double* __restrict__ stats) {
  __shared__ float sx[CIN * 64];
  int rec = blockIdx.x, t = threadIdx.x, lane = t & 63, wid = t >> 6;
  const float* zr = Z + (size_t)rec * ZSTRIDE;
  stage_bn<CIN>(zr, coefIn, sx, t);
  __syncthreads();
  int part = rec & 63;
  float acc[8];
#pragma unroll
  for (int g = 0; g < 4; ++g) {                 // 128 outs
    int o0 = wid + 32 * g;
    conv_sweep<CIN, 8>(w, o0, sx, lane, acc);
#pragma unroll
    for (int k = 0; k < 8; ++k) stat_accum(acc[k], o0 + 4 * k, 128, stats, part, lane);
  }
}

// ---------------- last layer, pass B: recompute conv + BN + ReLU + max over K + write --------
template <int CIN, int KNB>
__global__ __launch_bounds__(256) void convLastPool_kernel(
    const float* __restrict__ w, const float4* __restrict__ coefIn,
    const float4* __restrict__ coefOut,
    const float* __restrict__ Z, float* __restrict__ outFeats, int chBase) {
  __shared__ float sx[CIN * 64];
  int rec = blockIdx.x, t = threadIdx.x, lane = t & 63, wid = t >> 6;
  const float* zr = Z + (size_t)rec * ZSTRIDE;
  stage_bn<CIN>(zr, coefIn, sx, t);
  __syncthreads();
  float acc[8];
#pragma unroll
  for (int g = 0; g < 4; ++g) {
    int o0 = wid + 32 * g;
    conv_sweep<CIN, 8>(w, o0, sx, lane, acc);
#pragma unroll
    for (int k = 0; k < 8; ++k) {
      int o = o0 + 4 * k;
      float4 cf = coefOut[o];
      float z = fmaxf(((acc[k] - cf.x) * cf.y) * cf.z + cf.w, 0.f);
      if (KNB == 64) {
#pragma unroll
        for (int off = 1; off < 64; off <<= 1) z = fmaxf(z, __shfl_xor(z, off));
        if (lane == 0) {
          int b = rec >> 11, m = rec & 2047;
          outFeats[((size_t)b * 256 + chBase + o) * M_ + m] = z;
        }
      } else {                                  // KNB == 32: two groups per wave
#pragma unroll
        for (int off = 1; off < 32; off <<= 1) z = fmaxf(z, __shfl_xor(z, off));
        if ((lane & 31) == 0) {
          int grp = rec * 2 + (lane >> 5);
          int b = grp >> 11, m = grp & 2047;
          outFeats[((size_t)b * 256 + chBase + o) * M_ + m] = z;
        }
      }
    }
  }
}

// ---------------- fold fp64 BN stats into per-channel (mu, rstd, g, b) ----------------
__global__ void coef_kernel(const double* __restrict__ stats, const float* __restrict__ g,
                            const float* __restrict__ bb, float4* __restrict__ coef,
                            int cout, double invcnt) {
  int ch = threadIdx.x;
  if (ch >= cout) return;
  double s1 = 0.0, s2 = 0.0;
  for (int p = 0; p < 64; ++p) {
    s1 += stats[((size_t)p * 2 + 0) * cout + ch];
    s2 += stats[((size_t)p * 2 + 1) * cout + ch];
  }
  double mean = s1 * invcnt;
  double var = s2 * invcnt - mean * mean;
  double rstd = 1.0 / sqrt(var + 1e-5);
  coef[ch] = make_float4((float)mean, (float)rstd, g[ch], bb[ch]);
}

// ---------------- launcher ----------------
extern "C" void kernel_launch(void* const* d_in, const int* in_sizes, int n_in,
                              void* d_out, int out_size, void* d_ws, size_t ws_size,
                              hipStream_t stream) {
  const float* xyz  = (const float*)d_in[0];
  const float* feat = (const float*)d_in[1];
  const float* w00 = (const float*)d_in[2],  *g00 = (const float*)d_in[3],  *b00 = (const float*)d_in[4];
  const float* w01 = (const float*)d_in[5],  *g01 = (const float*)d_in[6],  *b01 = (const float*)d_in[7];
  const float* w02 = (const float*)d_in[8],  *g02 = (const float*)d_in[9],  *b02 = (const float*)d_in[10];
  const float* w10 = (const float*)d_in[11], *g10 = (const float*)d_in[12], *b10 = (const float*)d_in[13];
  const float* w11 = (const float*)d_in[14], *g11 = (const float*)d_in[15], *b11 = (const float*)d_in[16];
  const float* w12 = (const float*)d_in[17], *g12 = (const float*)d_in[18], *b12 = (const float*)d_in[19];

  char* ws = (char*)d_ws;
  float*  newxyz = (float*)(ws + OFF_NEWXYZ);
  int*    nidx0  = (int*)(ws + OFF_NIDX0);
  int*    nidx1  = (int*)(ws + OFF_NIDX1);
  double* stats  = (double*)(ws + OFF_STATS);
  float4* coef   = (float4*)(ws + OFF_COEF);
  float*  Z      = (float*)(ws + OFF_Z);
  float* outF = (float*)d_out;
  float* outFeats = outF + (size_t)B_ * 3 * M_;

  hipMemsetAsync(ws + OFF_STATS, 0, 6 * STATS_VALS * 8, stream);
  fps_kernel<<<B_, 512, 0, stream>>>(xyz, newxyz, outF);
  bq_kernel<32><<<(B_ * M_) / 4, 256, 0, stream>>>(xyz, newxyz, nidx0, (float)(0.2 * 0.2));
  bq_kernel<64><<<(B_ * M_) / 4, 256, 0, stream>>>(xyz, newxyz, nidx1, (float)(0.4 * 0.4));

  float4* c00 = coef + 0 * 128; float4* c01 = coef + 1 * 128; float4* c02 = coef + 2 * 128;
  float4* c10 = coef + 3 * 128; float4* c11 = coef + 4 * 128; float4* c12 = coef + 5 * 128;
  double* st0 = stats + 0 * STATS_VALS; double* st1 = stats + 1 * STATS_VALS;
  double* st2 = stats + 2 * STATS_VALS; double* st3 = stats + 3 * STATS_VALS;
  double* st4 = stats + 4 * STATS_VALS; double* st5 = stats + 5 * STATS_VALS;
  int gb0 = COLS0 / 64, gb1 = COLS1 / 64;       // one record per 256-thr block

  // ---- scale 0 (K=32): 67->64->64->128 ----
  convL0_kernel<32><<<gb0, 256, 0, stream>>>(w00, xyz, feat, nidx0, newxyz, Z, st0);
  coef_kernel<<<1, 128, 0, stream>>>(st0, g00, b00, c00, 64, 1.0 / COLS0);
  convMid_kernel<64, 64><<<gb0, 256, 0, stream>>>(w01, c00, Z, st1);
  coef_kernel<<<1, 128, 0, stream>>>(st1, g01, b01, c01, 64, 1.0 / COLS0);
  convLastStats_kernel<64><<<gb0, 256, 0, stream>>>(w02, c01, Z, st2);
  coef_kernel<<<1, 128, 0, stream>>>(st2, g02, b02, c02, 128, 1.0 / COLS0);
  convLastPool_kernel<64, 32><<<gb0, 256, 0, stream>>>(w02, c01, c02, Z, outFeats, 0);

  // ---- scale 1 (K=64): 67->64->96->128 ----
  convL0_kernel<64><<<gb1, 256, 0, stream>>>(w10, xyz, feat, nidx1, newxyz, Z, st3);
  coef_kernel<<<1, 128, 0, stream>>>(st3, g10, b10, c10, 64, 1.0 / COLS1);
  convMid_kernel<64, 96><<<gb1, 256, 0, stream>>>(w11, c10, Z, st4);
  coef_kernel<<<1, 128, 0, stream>>>(st4, g11, b11, c11, 96, 1.0 / COLS1);
  convLastStats_kernel<96><<<gb1, 256, 0, stream>>>(w12, c11, Z, st5);
  coef_kernel<<<1, 128, 0, stream>>>(st5, g12, b12, c12, 128, 1.0 / COLS1);
  convLastPool_kernel<96, 64><<<gb1, 256, 0, stream>>>(w12, c11, c12, Z, outFeats, 128);
}

// Round 8
// 5055.515 us; speedup vs baseline: 1.5105x; 1.0007x over previous
//
#include <hip/hip_runtime.h>
#include <cstdint>

// ---------------- problem constants ----------------
constexpr int B_ = 4, N_ = 16384, M_ = 2048;
constexpr int COLS0 = B_ * M_ * 32;   // 262144
constexpr int COLS1 = B_ * M_ * 64;   // 524288

// ---------------- workspace layout (bytes) ----------------
constexpr size_t OFF_NEWXYZ = 0;                                   // B*3*M fp32
constexpr size_t OFF_NIDX0  = (size_t)B_ * 3 * M_ * 4;             // 98304
constexpr size_t OFF_NIDX1  = OFF_NIDX0 + (size_t)COLS0 * 4;
constexpr size_t OFF_STATS  = OFF_NIDX1 + (size_t)COLS1 * 4;
constexpr size_t STATS_VALS = 64 * 2 * 128;                        // doubles per layer region
constexpr size_t OFF_COEF   = OFF_STATS + 6 * STATS_VALS * 8;      // 6 x 128 float4
constexpr size_t OFF_Z      = OFF_COEF + 6 * 128 * 16;
// Z: per-64-column records [rec][96 ch][64 lanes] fp32; COLS1/64 recs -> 201.3 MB
constexpr int ZSTRIDE = 96 * 64;                                   // floats per record

// ---------------- FPS v8: R0 structure + __launch_bounds__(512, 2) => VGPR cap 256 ----------
// Allocator-theory from the round ledger: VGPR counts track the compiler's occupancy TARGET
// exactly (R0: 512thr no-bound -> target 6 waves/EU -> cap 512/6=85 -> allocated 84, spilling
// the 128-float point set; R1: 1024thr -> target 8 -> 64 cap -> 56). Declaring min 2 waves/EU
// (= 1 workgroup/CU; grid is only B=4 blocks so higher occupancy is pure waste) raises the cap
// to 256: the 128 array floats + ~40 working regs now fit with NO spill. asm pin blocks remat.
// Arithmetic bit-identical to R0/R7 fps (contract off, (dx*dx+dy*dy)+dz*dz, min-update,
// strict-> argmax, packed-u64 tie-break -> min index).
__global__ __launch_bounds__(512, 2) void fps_kernel(const float* __restrict__ xyz,
                                                     float* __restrict__ newxyz,
                                                     float* __restrict__ outxyz) {
#pragma clang fp contract(off)
  int b = blockIdx.x, t = threadIdx.x;
  const float* xb = xyz + (size_t)b * 3 * N_;
  float px[32], py[32], pz[32], dd[32];
#pragma unroll
  for (int i = 0; i < 32; ++i) {
    int n = t + (i << 9);
    px[i] = xb[n]; py[i] = xb[N_ + n]; pz[i] = xb[2 * N_ + n];
    dd[i] = 1e10f;
    asm volatile("" : "+v"(px[i]), "+v"(py[i]), "+v"(pz[i]));   // forbid remat of point loads
  }
  __shared__ float s_out[3 * M_];
  __shared__ unsigned long long s_red[8];
  __shared__ int s_w;
  float fx = xb[0], fy = xb[N_], fz = xb[2 * N_];
  if (t == 0) { s_out[0] = fx; s_out[M_] = fy; s_out[2 * M_] = fz; }
  int lane = t & 63, wid = t >> 6;
  for (int s = 1; s < M_; ++s) {
    float bv = -1.f; int bi = 0;
#pragma unroll
    for (int i = 0; i < 32; ++i) {
      float dx = px[i] - fx, dy = py[i] - fy, dz = pz[i] - fz;
      float d = (dx * dx + dy * dy) + dz * dz;   // verbatim ref arithmetic (no FMA)
      float dm = dd[i];
      if (d < dm) dm = d;
      dd[i] = dm;
      if (dm > bv) { bv = dm; bi = t + (i << 9); }  // in-thread tie -> smaller n kept
    }
    // key: dist bits (>=0, monotone) high, ~idx low => max key = max dist, tie -> min idx
    unsigned long long key =
        ((unsigned long long)__float_as_uint(bv) << 32) | (unsigned)(0xFFFFFFFFu - (unsigned)bi);
#pragma unroll
    for (int off = 1; off < 64; off <<= 1) {
      unsigned long long o = __shfl_xor(key, off);
      if (o > key) key = o;
    }
    if (lane == 0) s_red[wid] = key;
    __syncthreads();
    if (wid == 0) {
      unsigned long long k2 = (lane < 8) ? s_red[lane] : 0ull;
#pragma unroll
      for (int off = 1; off < 8; off <<= 1) {
        unsigned long long o = __shfl_xor(k2, off);
        if (o > k2) k2 = o;
      }
      if (lane == 0) s_w = (int)(0xFFFFFFFFu - (unsigned)(k2 & 0xFFFFFFFFull));
    }
    __syncthreads();
    int w = s_w;
    fx = xb[w]; fy = xb[N_ + w]; fz = xb[2 * N_ + w];
    if (t == 0) { s_out[s] = fx; s_out[M_ + s] = fy; s_out[2 * M_ + s] = fz; }
  }
  __syncthreads();
  for (int e = t; e < 3 * M_; e += 512) {
    float v = s_out[e];
    newxyz[(size_t)b * 3 * M_ + e] = v;
    outxyz[(size_t)b * 3 * M_ + e] = v;
  }
}

// ---------------- ball query: wave per center, ballot-prefix, FMA dot (unchanged) -------------
template <int KNB>
__global__ __launch_bounds__(256) void bq_kernel(const float* __restrict__ xyz,
                                                 const float* __restrict__ newxyz,
                                                 int* __restrict__ nidx, float r2) {
#pragma clang fp contract(off)
  int t = threadIdx.x, lane = t & 63, wq = t >> 6;
  int q = blockIdx.x * 4 + wq;               // q < B*M
  int b = q >> 11, m = q & 2047;
  const float* xb = xyz + (size_t)b * 3 * N_;
  float cx = newxyz[((size_t)b * 3 + 0) * M_ + m];
  float cy = newxyz[((size_t)b * 3 + 1) * M_ + m];
  float cz = newxyz[((size_t)b * 3 + 2) * M_ + m];
  float sqc = (cx * cx + cy * cy) + cz * cz;         // no fma
  int found = 0, first = 0;
  for (int c = 0; c < N_ / 64; ++c) {
    int n = c * 64 + lane;
    float x = xb[n], y = xb[N_ + n], z = xb[2 * N_ + n];
    float sqx = (x * x + y * y) + z * z;             // no fma
    float dot = fmaf(cz, z, fmaf(cy, y, cx * x));    // fma chain (proven ref rounding)
    float d2 = (sqc + sqx) - 2.0f * dot;
    bool in = d2 < r2;
    unsigned long long mask = __ballot(in);
    if (mask) {
      if (found == 0) first = c * 64 + (__ffsll((long long)mask) - 1);
      int pos = found + __popcll(mask & ((1ull << lane) - 1ull));
      if (in && pos < KNB) nidx[(size_t)q * KNB + pos] = n;
      found += __popcll(mask);
      if (found >= KNB) break;
    }
  }
  if (found < KNB) {
    int fill = (found == 0) ? 0 : first;
    for (int s = found + lane; s < KNB; s += 64) nidx[(size_t)q * KNB + s] = fill;
  }
}

// ---------------- per-channel stats: fp32 butterfly partials -> f64 bucketed atomics ----------
__device__ __forceinline__ void stat_accum(float acc, int o, int cout, double* stats,
                                           int part, int lane) {
  float v1 = acc, v2 = acc * acc;
#pragma unroll
  for (int off = 1; off < 64; off <<= 1) {
    v1 += __shfl_xor(v1, off);
    v2 += __shfl_xor(v2, off);
  }
  if (lane == 0) {
    atomicAdd(stats + ((size_t)part * 2 + 0) * cout + o, (double)v1);
    atomicAdd(stats + ((size_t)part * 2 + 1) * cout + o, (double)v2);
  }
}

// ---------------- conv (R7, proven): LDS tile + uniform sgpr weight base ---------------------
template <int CIN, int G>
__device__ __forceinline__ void conv_sweep(const float* __restrict__ w, int o0,
                                           const float* sx, int lane, float* acc) {
  int o0u = __builtin_amdgcn_readfirstlane(o0);       // exact: o0 is wave-uniform
  const float* wb = w + (size_t)o0u * CIN;            // SGPR base -> s_load weights
#pragma unroll
  for (int k = 0; k < G; ++k) acc[k] = 0.f;
#pragma unroll 8
  for (int c = 0; c < CIN; ++c) {
    float xv = sx[c * 64 + lane];
#pragma unroll
    for (int k = 0; k < G; ++k) acc[k] += wb[(size_t)(4 * k) * CIN + c] * xv;
  }
}

// stage BN(ReLU(zr)) tile -> sx, float4 path (Z records are 16B-aligned)
template <int CIN>
__device__ __forceinline__ void stage_bn(const float* __restrict__ zr,
                                         const float4* __restrict__ coefIn,
                                         float* sx, int t) {
  const float4* zr4 = (const float4*)zr;
  float4* sx4 = (float4*)sx;
  for (int e = t; e < CIN * 16; e += 256) {
    int c = e >> 4;
    float4 v = zr4[e];
    float4 cf = coefIn[c];
    float4 r;
    r.x = fmaxf(((v.x - cf.x) * cf.y) * cf.z + cf.w, 0.f);
    r.y = fmaxf(((v.y - cf.x) * cf.y) * cf.z + cf.w, 0.f);
    r.z = fmaxf(((v.z - cf.x) * cf.y) * cf.z + cf.w, 0.f);
    r.w = fmaxf(((v.w - cf.x) * cf.y) * cf.z + cf.w, 0.f);
    sx4[e] = r;
  }
}

// ---------------- layer 0: gather once -> LDS -> conv(67->64) + stats ------------------------
template <int KNB>
__global__ __launch_bounds__(256) void convL0_kernel(
    const float* __restrict__ w0, const float* __restrict__ xyz,
    const float* __restrict__ feat, const int* __restrict__ nidx,
    const float* __restrict__ newxyz, float* __restrict__ Z, double* __restrict__ stats) {
  __shared__ float sx[67 * 64];                 // 17152 B
  __shared__ int snb[64];
  int rec = blockIdx.x, t = threadIdx.x, lane = t & 63, wid = t >> 6;
  if (t < 64) snb[t] = nidx[(size_t)rec * 64 + t];
  __syncthreads();
  for (int e = t; e < 67 * 64; e += 256) {      // each input element fetched exactly once
    int c = e >> 6, l = e & 63;
    int col = rec * 64 + l;
    int b = col / (M_ * KNB);
    int rem = col - b * (M_ * KNB);
    int m = rem / KNB;
    int n = snb[l];
    float v;
    if (c < 3) v = xyz[((size_t)b * 3 + c) * N_ + n] - newxyz[((size_t)b * 3 + c) * M_ + m];
    else       v = feat[((size_t)b * 64 + (c - 3)) * N_ + n];
    sx[e] = v;
  }
  __syncthreads();
  float* zr = Z + (size_t)rec * ZSTRIDE;
  int part = rec & 63;
  float acc[8];
#pragma unroll
  for (int g = 0; g < 2; ++g) {                 // 16 outs/wave: o = wid + 32g + 4k
    int o0 = wid + 32 * g;
    conv_sweep<67, 8>(w0, o0, sx, lane, acc);
#pragma unroll
    for (int k = 0; k < 8; ++k) {
      int o = o0 + 4 * k;
      zr[o * 64 + lane] = acc[k];
      stat_accum(acc[k], o, 64, stats, part, lane);
    }
  }
}

// ---------------- mid layer: BN-stage -> conv -> in-place store + stats ----------------------
template <int CIN, int COUT>
__global__ __launch_bounds__(256) void convMid_kernel(
    const float* __restrict__ w, const float4* __restrict__ coefIn,
    float* __restrict__ Z, double* __restrict__ stats) {
  __shared__ float sx[CIN * 64];
  int rec = blockIdx.x, t = threadIdx.x, lane = t & 63, wid = t >> 6;
  float* zr = Z + (size_t)rec * ZSTRIDE;
  stage_bn<CIN>(zr, coefIn, sx, t);
  __syncthreads();                              // all reads done -> safe in-place overwrite
  int part = rec & 63;
  float acc[8];
#pragma unroll
  for (int g = 0; g < COUT / 32; ++g) {
    int o0 = wid + 32 * g;
    conv_sweep<CIN, 8>(w, o0, sx, lane, acc);
#pragma unroll
    for (int k = 0; k < 8; ++k) {
      int o = o0 + 4 * k;
      zr[o * 64 + lane] = acc[k];
      stat_accum(acc[k], o, COUT, stats, part, lane);
    }
  }
}

// ---------------- last layer, pass A: stats only ---------------------------------------------
template <int CIN>
__global__ __launch_bounds__(256) void convLastStats_kernel(
    const float* __restrict__ w, const float4* __restrict__ coefIn,
    const float* __restrict__ Z, double* __restrict__ stats) {
  __shared__ float sx[CIN * 64];
  int rec = blockIdx.x, t = threadIdx.x, lane = t & 63, wid = t >> 6;
  const float* zr = Z + (size_t)rec * ZSTRIDE;
  stage_bn<CIN>(zr, coefIn, sx, t);
  __syncthreads();
  int part = rec & 63;
  float acc[8];
#pragma unroll
  for (int g = 0; g < 4; ++g) {                 // 128 outs
    int o0 = wid + 32 * g;
    conv_sweep<CIN, 8>(w, o0, sx, lane, acc);
#pragma unroll
    for (int k = 0; k < 8; ++k) stat_accum(acc[k], o0 + 4 * k, 128, stats, part, lane);
  }
}

// ---------------- last layer, pass B: recompute conv + BN + ReLU + max over K + write --------
template <int CIN, int KNB>
__global__ __launch_bounds__(256) void convLastPool_kernel(
    const float* __restrict__ w, const float4* __restrict__ coefIn,
    const float4* __restrict__ coefOut,
    const float* __restrict__ Z, float* __restrict__ outFeats, int chBase) {
  __shared__ float sx[CIN * 64];
  int rec = blockIdx.x, t = threadIdx.x, lane = t & 63, wid = t >> 6;
  const float* zr = Z + (size_t)rec * ZSTRIDE;
  stage_bn<CIN>(zr, coefIn, sx, t);
  __syncthreads();
  float acc[8];
#pragma unroll
  for (int g = 0; g < 4; ++g) {
    int o0 = wid + 32 * g;
    conv_sweep<CIN, 8>(w, o0, sx, lane, acc);
#pragma unroll
    for (int k = 0; k < 8; ++k) {
      int o = o0 + 4 * k;
      float4 cf = coefOut[o];
      float z = fmaxf(((acc[k] - cf.x) * cf.y) * cf.z + cf.w, 0.f);
      if (KNB == 64) {
#pragma unroll
        for (int off = 1; off < 64; off <<= 1) z = fmaxf(z, __shfl_xor(z, off));
        if (lane == 0) {
          int b = rec >> 11, m = rec & 2047;
          outFeats[((size_t)b * 256 + chBase + o) * M_ + m] = z;
        }
      } else {                                  // KNB == 32: two groups per wave
#pragma unroll
        for (int off = 1; off < 32; off <<= 1) z = fmaxf(z, __shfl_xor(z, off));
        if ((lane & 31) == 0) {
          int grp = rec * 2 + (lane >> 5);
          int b = grp >> 11, m = grp & 2047;
          outFeats[((size_t)b * 256 + chBase + o) * M_ + m] = z;
        }
      }
    }
  }
}

// ---------------- fold fp64 BN stats into per-channel (mu, rstd, g, b) ----------------
__global__ void coef_kernel(const double* __restrict__ stats, const float* __restrict__ g,
                            const float* __restrict__ bb, float4* __restrict__ coef,
                            int cout, double invcnt) {
  int ch = threadIdx.x;
  if (ch >= cout) return;
  double s1 = 0.0, s2 = 0.0;
  for (int p = 0; p < 64; ++p) {
    s1 += stats[((size_t)p * 2 + 0) * cout + ch];
    s2 += stats[((size_t)p * 2 + 1) * cout + ch];
  }
  double mean = s1 * invcnt;
  double var = s2 * invcnt - mean * mean;
  double rstd = 1.0 / sqrt(var + 1e-5);
  coef[ch] = make_float4((float)mean, (float)rstd, g[ch], bb[ch]);
}

// ---------------- launcher ----------------
extern "C" void kernel_launch(void* const* d_in, const int* in_sizes, int n_in,
                              void* d_out, int out_size, void* d_ws, size_t ws_size,
                              hipStream_t stream) {
  const float* xyz  = (const float*)d_in[0];
  const float* feat = (const float*)d_in[1];
  const float* w00 = (const float*)d_in[2],  *g00 = (const float*)d_in[3],  *b00 = (const float*)d_in[4];
  const float* w01 = (const float*)d_in[5],  *g01 = (const float*)d_in[6],  *b01 = (const float*)d_in[7];
  const float* w02 = (const float*)d_in[8],  *g02 = (const float*)d_in[9],  *b02 = (const float*)d_in[10];
  const float* w10 = (const float*)d_in[11], *g10 = (const float*)d_in[12], *b10 = (const float*)d_in[13];
  const float* w11 = (const float*)d_in[14], *g11 = (const float*)d_in[15], *b11 = (const float*)d_in[16];
  const float* w12 = (const float*)d_in[17], *g12 = (const float*)d_in[18], *b12 = (const float*)d_in[19];

  char* ws = (char*)d_ws;
  float*  newxyz = (float*)(ws + OFF_NEWXYZ);
  int*    nidx0  = (int*)(ws + OFF_NIDX0);
  int*    nidx1  = (int*)(ws + OFF_NIDX1);
  double* stats  = (double*)(ws + OFF_STATS);
  float4* coef   = (float4*)(ws + OFF_COEF);
  float*  Z      = (float*)(ws + OFF_Z);
  float* outF = (float*)d_out;
  float* outFeats = outF + (size_t)B_ * 3 * M_;

  hipMemsetAsync(ws + OFF_STATS, 0, 6 * STATS_VALS * 8, stream);
  fps_kernel<<<B_, 512, 0, stream>>>(xyz, newxyz, outF);
  bq_kernel<32><<<(B_ * M_) / 4, 256, 0, stream>>>(xyz, newxyz, nidx0, (float)(0.2 * 0.2));
  bq_kernel<64><<<(B_ * M_) / 4, 256, 0, stream>>>(xyz, newxyz, nidx1, (float)(0.4 * 0.4));

  float4* c00 = coef + 0 * 128; float4* c01 = coef + 1 * 128; float4* c02 = coef + 2 * 128;
  float4* c10 = coef + 3 * 128; float4* c11 = coef + 4 * 128; float4* c12 = coef + 5 * 128;
  double* st0 = stats + 0 * STATS_VALS; double* st1 = stats + 1 * STATS_VALS;
  double* st2 = stats + 2 * STATS_VALS; double* st3 = stats + 3 * STATS_VALS;
  double* st4 = stats + 4 * STATS_VALS; double* st5 = stats + 5 * STATS_VALS;
  int gb0 = COLS0 / 64, gb1 = COLS1 / 64;       // one record per 256-thr block

  // ---- scale 0 (K=32): 67->64->64->128 ----
  convL0_kernel<32><<<gb0, 256, 0, stream>>>(w00, xyz, feat, nidx0, newxyz, Z, st0);
  coef_kernel<<<1, 128, 0, stream>>>(st0, g00, b00, c00, 64, 1.0 / COLS0);
  convMid_kernel<64, 64><<<gb0, 256, 0, stream>>>(w01, c00, Z, st1);
  coef_kernel<<<1, 128, 0, stream>>>(st1, g01, b01, c01, 64, 1.0 / COLS0);
  convLastStats_kernel<64><<<gb0, 256, 0, stream>>>(w02, c01, Z, st2);
  coef_kernel<<<1, 128, 0, stream>>>(st2, g02, b02, c02, 128, 1.0 / COLS0);
  convLastPool_kernel<64, 32><<<gb0, 256, 0, stream>>>(w02, c01, c02, Z, outFeats, 0);

  // ---- scale 1 (K=64): 67->64->96->128 ----
  convL0_kernel<64><<<gb1, 256, 0, stream>>>(w10, xyz, feat, nidx1, newxyz, Z, st3);
  coef_kernel<<<1, 128, 0, stream>>>(st3, g10, b10, c10, 64, 1.0 / COLS1);
  convMid_kernel<64, 96><<<gb1, 256, 0, stream>>>(w11, c10, Z, st4);
  coef_kernel<<<1, 128, 0, stream>>>(st4, g11, b11, c11, 96, 1.0 / COLS1);
  convLastStats_kernel<96><<<gb1, 256, 0, stream>>>(w12, c11, Z, st5);
  coef_kernel<<<1, 128, 0, stream>>>(st5, g12, b12, c12, 128, 1.0 / COLS1);
  convLastPool_kernel<96, 64><<<gb1, 256, 0, stream>>>(w12, c11, c12, Z, outFeats, 128);
}

// Round 9
// 4897.583 us; speedup vs baseline: 1.5592x; 1.0322x over previous
//
#include <hip/hip_runtime.h>
#include <cstdint>

// ---------------- problem constants ----------------
constexpr int B_ = 4, N_ = 16384, M_ = 2048;
constexpr int COLS0 = B_ * M_ * 32;   // 262144
constexpr int COLS1 = B_ * M_ * 64;   // 524288

// ---------------- workspace layout (bytes) ----------------
constexpr size_t OFF_NEWXYZ = 0;                                   // B*3*M fp32
constexpr size_t OFF_NIDX0  = (size_t)B_ * 3 * M_ * 4;             // 98304
constexpr size_t OFF_NIDX1  = OFF_NIDX0 + (size_t)COLS0 * 4;
constexpr size_t OFF_STATS  = OFF_NIDX1 + (size_t)COLS1 * 4;
constexpr size_t STATS_VALS = 64 * 2 * 128;                        // doubles per layer region
constexpr size_t OFF_COEF   = OFF_STATS + 6 * STATS_VALS * 8;      // 6 x 128 float4
constexpr size_t OFF_MNMX   = OFF_COEF + 6 * 128 * 16;             // 4 x (B*M*128) fp32 = 16MB
constexpr size_t MNMX_ONE   = (size_t)B_ * M_ * 128 * 4;
constexpr size_t OFF_Z      = OFF_MNMX + 4 * MNMX_ONE;
// Z: per-64-column records [rec][96 ch][64 lanes] fp32; COLS1/64 recs -> 201.3 MB (~222MB total)
constexpr int ZSTRIDE = 96 * 64;                                   // floats per record

// ---------------- FPS (closed at 3.68ms): R0 structure; 5 structural attempts all >= this ----
__global__ __launch_bounds__(512, 2) void fps_kernel(const float* __restrict__ xyz,
                                                     float* __restrict__ newxyz,
                                                     float* __restrict__ outxyz) {
#pragma clang fp contract(off)
  int b = blockIdx.x, t = threadIdx.x;
  const float* xb = xyz + (size_t)b * 3 * N_;
  float px[32], py[32], pz[32], dd[32];
#pragma unroll
  for (int i = 0; i < 32; ++i) {
    int n = t + (i << 9);
    px[i] = xb[n]; py[i] = xb[N_ + n]; pz[i] = xb[2 * N_ + n];
    dd[i] = 1e10f;
    asm volatile("" : "+v"(px[i]), "+v"(py[i]), "+v"(pz[i]));
  }
  __shared__ float s_out[3 * M_];
  __shared__ unsigned long long s_red[8];
  __shared__ int s_w;
  float fx = xb[0], fy = xb[N_], fz = xb[2 * N_];
  if (t == 0) { s_out[0] = fx; s_out[M_] = fy; s_out[2 * M_] = fz; }
  int lane = t & 63, wid = t >> 6;
  for (int s = 1; s < M_; ++s) {
    float bv = -1.f; int bi = 0;
#pragma unroll
    for (int i = 0; i < 32; ++i) {
      float dx = px[i] - fx, dy = py[i] - fy, dz = pz[i] - fz;
      float d = (dx * dx + dy * dy) + dz * dz;   // verbatim ref arithmetic (no FMA)
      float dm = dd[i];
      if (d < dm) dm = d;
      dd[i] = dm;
      if (dm > bv) { bv = dm; bi = t + (i << 9); }  // in-thread tie -> smaller n kept
    }
    unsigned long long key =
        ((unsigned long long)__float_as_uint(bv) << 32) | (unsigned)(0xFFFFFFFFu - (unsigned)bi);
#pragma unroll
    for (int off = 1; off < 64; off <<= 1) {
      unsigned long long o = __shfl_xor(key, off);
      if (o > key) key = o;
    }
    if (lane == 0) s_red[wid] = key;
    __syncthreads();
    if (wid == 0) {
      unsigned long long k2 = (lane < 8) ? s_red[lane] : 0ull;
#pragma unroll
      for (int off = 1; off < 8; off <<= 1) {
        unsigned long long o = __shfl_xor(k2, off);
        if (o > k2) k2 = o;
      }
      if (lane == 0) s_w = (int)(0xFFFFFFFFu - (unsigned)(k2 & 0xFFFFFFFFull));
    }
    __syncthreads();
    int w = s_w;
    fx = xb[w]; fy = xb[N_ + w]; fz = xb[2 * N_ + w];
    if (t == 0) { s_out[s] = fx; s_out[M_ + s] = fy; s_out[2 * M_ + s] = fz; }
  }
  __syncthreads();
  for (int e = t; e < 3 * M_; e += 512) {
    float v = s_out[e];
    newxyz[(size_t)b * 3 * M_ + e] = v;
    outxyz[(size_t)b * 3 * M_ + e] = v;
  }
}

// ---------------- ball query: wave per center, ballot-prefix, FMA dot (unchanged) -------------
template <int KNB>
__global__ __launch_bounds__(256) void bq_kernel(const float* __restrict__ xyz,
                                                 const float* __restrict__ newxyz,
                                                 int* __restrict__ nidx, float r2) {
#pragma clang fp contract(off)
  int t = threadIdx.x, lane = t & 63, wq = t >> 6;
  int q = blockIdx.x * 4 + wq;               // q < B*M
  int b = q >> 11, m = q & 2047;
  const float* xb = xyz + (size_t)b * 3 * N_;
  float cx = newxyz[((size_t)b * 3 + 0) * M_ + m];
  float cy = newxyz[((size_t)b * 3 + 1) * M_ + m];
  float cz = newxyz[((size_t)b * 3 + 2) * M_ + m];
  float sqc = (cx * cx + cy * cy) + cz * cz;         // no fma
  int found = 0, first = 0;
  for (int c = 0; c < N_ / 64; ++c) {
    int n = c * 64 + lane;
    float x = xb[n], y = xb[N_ + n], z = xb[2 * N_ + n];
    float sqx = (x * x + y * y) + z * z;             // no fma
    float dot = fmaf(cz, z, fmaf(cy, y, cx * x));    // fma chain (proven ref rounding)
    float d2 = (sqc + sqx) - 2.0f * dot;
    bool in = d2 < r2;
    unsigned long long mask = __ballot(in);
    if (mask) {
      if (found == 0) first = c * 64 + (__ffsll((long long)mask) - 1);
      int pos = found + __popcll(mask & ((1ull << lane) - 1ull));
      if (in && pos < KNB) nidx[(size_t)q * KNB + pos] = n;
      found += __popcll(mask);
      if (found >= KNB) break;
    }
  }
  if (found < KNB) {
    int fill = (found == 0) ? 0 : first;
    for (int s = found + lane; s < KNB; s += 64) nidx[(size_t)q * KNB + s] = fill;
  }
}

// ---------------- per-channel stats: fp32 butterfly partials -> f64 bucketed atomics ----------
__device__ __forceinline__ void stat_accum(float acc, int o, int cout, double* stats,
                                           int part, int lane) {
  float v1 = acc, v2 = acc * acc;
#pragma unroll
  for (int off = 1; off < 64; off <<= 1) {
    v1 += __shfl_xor(v1, off);
    v2 += __shfl_xor(v2, off);
  }
  if (lane == 0) {
    atomicAdd(stats + ((size_t)part * 2 + 0) * cout + o, (double)v1);
    atomicAdd(stats + ((size_t)part * 2 + 1) * cout + o, (double)v2);
  }
}

// ---------------- conv (R7, proven): LDS tile + uniform sgpr weight base ---------------------
template <int CIN, int G>
__device__ __forceinline__ void conv_sweep(const float* __restrict__ w, int o0,
                                           const float* sx, int lane, float* acc) {
  int o0u = __builtin_amdgcn_readfirstlane(o0);       // exact: o0 is wave-uniform
  const float* wb = w + (size_t)o0u * CIN;            // SGPR base -> s_load weights
#pragma unroll
  for (int k = 0; k < G; ++k) acc[k] = 0.f;
#pragma unroll 8
  for (int c = 0; c < CIN; ++c) {
    float xv = sx[c * 64 + lane];
#pragma unroll
    for (int k = 0; k < G; ++k) acc[k] += wb[(size_t)(4 * k) * CIN + c] * xv;
  }
}

// stage BN(ReLU(zr)) tile -> sx, float4 path (Z records are 16B-aligned)
template <int CIN>
__device__ __forceinline__ void stage_bn(const float* __restrict__ zr,
                                         const float4* __restrict__ coefIn,
                                         float* sx, int t) {
  const float4* zr4 = (const float4*)zr;
  float4* sx4 = (float4*)sx;
  for (int e = t; e < CIN * 16; e += 256) {
    int c = e >> 4;
    float4 v = zr4[e];
    float4 cf = coefIn[c];
    float4 r;
    r.x = fmaxf(((v.x - cf.x) * cf.y) * cf.z + cf.w, 0.f);
    r.y = fmaxf(((v.y - cf.x) * cf.y) * cf.z + cf.w, 0.f);
    r.z = fmaxf(((v.z - cf.x) * cf.y) * cf.z + cf.w, 0.f);
    r.w = fmaxf(((v.w - cf.x) * cf.y) * cf.z + cf.w, 0.f);
    sx4[e] = r;
  }
}

// ---------------- layer 0: gather once -> LDS -> conv(67->64) + stats ------------------------
template <int KNB>
__global__ __launch_bounds__(256) void convL0_kernel(
    const float* __restrict__ w0, const float* __restrict__ xyz,
    const float* __restrict__ feat, const int* __restrict__ nidx,
    const float* __restrict__ newxyz, float* __restrict__ Z, double* __restrict__ stats) {
  __shared__ float sx[67 * 64];                 // 17152 B
  __shared__ int snb[64];
  int rec = blockIdx.x, t = threadIdx.x, lane = t & 63, wid = t >> 6;
  if (t < 64) snb[t] = nidx[(size_t)rec * 64 + t];
  __syncthreads();
  for (int e = t; e < 67 * 64; e += 256) {      // each input element fetched exactly once
    int c = e >> 6, l = e & 63;
    int col = rec * 64 + l;
    int b = col / (M_ * KNB);
    int rem = col - b * (M_ * KNB);
    int m = rem / KNB;
    int n = snb[l];
    float v;
    if (c < 3) v = xyz[((size_t)b * 3 + c) * N_ + n] - newxyz[((size_t)b * 3 + c) * M_ + m];
    else       v = feat[((size_t)b * 64 + (c - 3)) * N_ + n];
    sx[e] = v;
  }
  __syncthreads();
  float* zr = Z + (size_t)rec * ZSTRIDE;
  int part = rec & 63;
  float acc[8];
#pragma unroll
  for (int g = 0; g < 2; ++g) {                 // 16 outs/wave: o = wid + 32g + 4k
    int o0 = wid + 32 * g;
    conv_sweep<67, 8>(w0, o0, sx, lane, acc);
#pragma unroll
    for (int k = 0; k < 8; ++k) {
      int o = o0 + 4 * k;
      zr[o * 64 + lane] = acc[k];
      stat_accum(acc[k], o, 64, stats, part, lane);
    }
  }
}

// ---------------- mid layer: BN-stage -> conv -> in-place store + stats ----------------------
template <int CIN, int COUT>
__global__ __launch_bounds__(256) void convMid_kernel(
    const float* __restrict__ w, const float4* __restrict__ coefIn,
    float* __restrict__ Z, double* __restrict__ stats) {
  __shared__ float sx[CIN * 64];
  int rec = blockIdx.x, t = threadIdx.x, lane = t & 63, wid = t >> 6;
  float* zr = Z + (size_t)rec * ZSTRIDE;
  stage_bn<CIN>(zr, coefIn, sx, t);
  __syncthreads();                              // all reads done -> safe in-place overwrite
  int part = rec & 63;
  float acc[8];
#pragma unroll
  for (int g = 0; g < COUT / 32; ++g) {
    int o0 = wid + 32 * g;
    conv_sweep<CIN, 8>(w, o0, sx, lane, acc);
#pragma unroll
    for (int k = 0; k < 8; ++k) {
      int o = o0 + 4 * k;
      zr[o * 64 + lane] = acc[k];
      stat_accum(acc[k], o, COUT, stats, part, lane);
    }
  }
}

// ---------------- last layer (SINGLE pass): conv + stats + raw min/max over K ----------------
// R8 post-mortem: layer-2 conv was computed twice (stats pass + pool pass re-reading Z).
// Monotonicity makes the recompute unnecessary and is BIT-EXACT: every BN step (-mu, *rstd>0,
// *g, +b) is a monotone fp op with a fixed second operand, so
//   max_k ReLU(BN(z_k)) = ReLU(fmax(BN(max_k z), BN(min_k z)))
// (g>=0 -> BN(max); g<0 -> BN(min); fmax covers both; ReLU monotone). We reduce RAW conv
// outputs over k here (cheap shuffles) and apply coefOut in a tiny elementwise finalize.
template <int CIN, int KNB>
__global__ __launch_bounds__(256) void convLast_kernel(
    const float* __restrict__ w, const float4* __restrict__ coefIn,
    const float* __restrict__ Z, double* __restrict__ stats,
    float* __restrict__ mx, float* __restrict__ mn) {
  __shared__ float sx[CIN * 64];
  int rec = blockIdx.x, t = threadIdx.x, lane = t & 63, wid = t >> 6;
  const float* zr = Z + (size_t)rec * ZSTRIDE;
  stage_bn<CIN>(zr, coefIn, sx, t);
  __syncthreads();
  int part = rec & 63;
  float acc[8];
#pragma unroll
  for (int g = 0; g < 4; ++g) {                 // 128 outs
    int o0 = wid + 32 * g;
    conv_sweep<CIN, 8>(w, o0, sx, lane, acc);
#pragma unroll
    for (int k = 0; k < 8; ++k) {
      int o = o0 + 4 * k;
      stat_accum(acc[k], o, 128, stats, part, lane);
      float vM = acc[k], vN = acc[k];
      if (KNB == 64) {
#pragma unroll
        for (int off = 1; off < 64; off <<= 1) {
          vM = fmaxf(vM, __shfl_xor(vM, off));
          vN = fminf(vN, __shfl_xor(vN, off));
        }
        if (lane == 0) {
          mx[(size_t)o * (B_ * M_) + rec] = vM;
          mn[(size_t)o * (B_ * M_) + rec] = vN;
        }
      } else {                                  // KNB == 32: two centers per wave
#pragma unroll
        for (int off = 1; off < 32; off <<= 1) {
          vM = fmaxf(vM, __shfl_xor(vM, off));
          vN = fminf(vN, __shfl_xor(vN, off));
        }
        if ((lane & 31) == 0) {
          int grp = rec * 2 + (lane >> 5);      // global center index (b*M+m)
          mx[(size_t)o * (B_ * M_) + grp] = vM;
          mn[(size_t)o * (B_ * M_) + grp] = vN;
        }
      }
    }
  }
}

// ---------------- finalize: out = ReLU(fmax(BN(mx), BN(mn))), ref op order -------------------
__global__ __launch_bounds__(256) void pool_fin_kernel(
    const float* __restrict__ mx, const float* __restrict__ mn,
    const float4* __restrict__ coefOut, float* __restrict__ outFeats, int chBase) {
  int idx = blockIdx.x * 256 + threadIdx.x;     // < 128 * B*M
  int o = idx >> 13;                            // B*M = 8192
  int gm = idx & 8191;
  float4 cf = coefOut[o];
  float vM = mx[idx], vN = mn[idx];
  float rM = ((vM - cf.x) * cf.y) * cf.z + cf.w;   // ref op order
  float rN = ((vN - cf.x) * cf.y) * cf.z + cf.w;
  float z = fmaxf(fmaxf(rM, rN), 0.f);
  int b = gm >> 11, m = gm & 2047;
  outFeats[((size_t)b * 256 + chBase + o) * M_ + m] = z;
}

// ---------------- fold fp64 BN stats into per-channel (mu, rstd, g, b) ----------------
__global__ void coef_kernel(const double* __restrict__ stats, const float* __restrict__ g,
                            const float* __restrict__ bb, float4* __restrict__ coef,
                            int cout, double invcnt) {
  int ch = threadIdx.x;
  if (ch >= cout) return;
  double s1 = 0.0, s2 = 0.0;
  for (int p = 0; p < 64; ++p) {
    s1 += stats[((size_t)p * 2 + 0) * cout + ch];
    s2 += stats[((size_t)p * 2 + 1) * cout + ch];
  }
  double mean = s1 * invcnt;
  double var = s2 * invcnt - mean * mean;
  double rstd = 1.0 / sqrt(var + 1e-5);
  coef[ch] = make_float4((float)mean, (float)rstd, g[ch], bb[ch]);
}

// ---------------- launcher ----------------
extern "C" void kernel_launch(void* const* d_in, const int* in_sizes, int n_in,
                              void* d_out, int out_size, void* d_ws, size_t ws_size,
                              hipStream_t stream) {
  const float* xyz  = (const float*)d_in[0];
  const float* feat = (const float*)d_in[1];
  const float* w00 = (const float*)d_in[2],  *g00 = (const float*)d_in[3],  *b00 = (const float*)d_in[4];
  const float* w01 = (const float*)d_in[5],  *g01 = (const float*)d_in[6],  *b01 = (const float*)d_in[7];
  const float* w02 = (const float*)d_in[8],  *g02 = (const float*)d_in[9],  *b02 = (const float*)d_in[10];
  const float* w10 = (const float*)d_in[11], *g10 = (const float*)d_in[12], *b10 = (const float*)d_in[13];
  const float* w11 = (const float*)d_in[14], *g11 = (const float*)d_in[15], *b11 = (const float*)d_in[16];
  const float* w12 = (const float*)d_in[17], *g12 = (const float*)d_in[18], *b12 = (const float*)d_in[19];

  char* ws = (char*)d_ws;
  float*  newxyz = (float*)(ws + OFF_NEWXYZ);
  int*    nidx0  = (int*)(ws + OFF_NIDX0);
  int*    nidx1  = (int*)(ws + OFF_NIDX1);
  double* stats  = (double*)(ws + OFF_STATS);
  float4* coef   = (float4*)(ws + OFF_COEF);
  float*  mx0    = (float*)(ws + OFF_MNMX + 0 * MNMX_ONE);
  float*  mn0    = (float*)(ws + OFF_MNMX + 1 * MNMX_ONE);
  float*  mx1    = (float*)(ws + OFF_MNMX + 2 * MNMX_ONE);
  float*  mn1    = (float*)(ws + OFF_MNMX + 3 * MNMX_ONE);
  float*  Z      = (float*)(ws + OFF_Z);
  float* outF = (float*)d_out;
  float* outFeats = outF + (size_t)B_ * 3 * M_;

  hipMemsetAsync(ws + OFF_STATS, 0, 6 * STATS_VALS * 8, stream);
  fps_kernel<<<B_, 512, 0, stream>>>(xyz, newxyz, outF);
  bq_kernel<32><<<(B_ * M_) / 4, 256, 0, stream>>>(xyz, newxyz, nidx0, (float)(0.2 * 0.2));
  bq_kernel<64><<<(B_ * M_) / 4, 256, 0, stream>>>(xyz, newxyz, nidx1, (float)(0.4 * 0.4));

  float4* c00 = coef + 0 * 128; float4* c01 = coef + 1 * 128; float4* c02 = coef + 2 * 128;
  float4* c10 = coef + 3 * 128; float4* c11 = coef + 4 * 128; float4* c12 = coef + 5 * 128;
  double* st0 = stats + 0 * STATS_VALS; double* st1 = stats + 1 * STATS_VALS;
  double* st2 = stats + 2 * STATS_VALS; double* st3 = stats + 3 * STATS_VALS;
  double* st4 = stats + 4 * STATS_VALS; double* st5 = stats + 5 * STATS_VALS;
  int gb0 = COLS0 / 64, gb1 = COLS1 / 64;       // one record per 256-thr block
  int gfin = (128 * B_ * M_) / 256;             // finalize grid

  // ---- scale 0 (K=32): 67->64->64->128 ----
  convL0_kernel<32><<<gb0, 256, 0, stream>>>(w00, xyz, feat, nidx0, newxyz, Z, st0);
  coef_kernel<<<1, 128, 0, stream>>>(st0, g00, b00, c00, 64, 1.0 / COLS0);
  convMid_kernel<64, 64><<<gb0, 256, 0, stream>>>(w01, c00, Z, st1);
  coef_kernel<<<1, 128, 0, stream>>>(st1, g01, b01, c01, 64, 1.0 / COLS0);
  convLast_kernel<64, 32><<<gb0, 256, 0, stream>>>(w02, c01, Z, st2, mx0, mn0);
  coef_kernel<<<1, 128, 0, stream>>>(st2, g02, b02, c02, 128, 1.0 / COLS0);
  pool_fin_kernel<<<gfin, 256, 0, stream>>>(mx0, mn0, c02, outFeats, 0);

  // ---- scale 1 (K=64): 67->64->96->128 ----
  convL0_kernel<64><<<gb1, 256, 0, stream>>>(w10, xyz, feat, nidx1, newxyz, Z, st3);
  coef_kernel<<<1, 128, 0, stream>>>(st3, g10, b10, c10, 64, 1.0 / COLS1);
  convMid_kernel<64, 96><<<gb1, 256, 0, stream>>>(w11, c10, Z, st4);
  coef_kernel<<<1, 128, 0, stream>>>(st4, g11, b11, c11, 96, 1.0 / COLS1);
  convLast_kernel<96, 64><<<gb1, 256, 0, stream>>>(w12, c11, Z, st5, mx1, mn1);
  coef_kernel<<<1, 128, 0, stream>>>(st5, g12, b12, c12, 128, 1.0 / COLS1);
  pool_fin_kernel<<<gfin, 256, 0, stream>>>(mx1, mn1, c12, outFeats, 128);
}